// Round 11
// baseline (162.337 us; speedup 1.0000x reference)
//
#include <hip/hip_runtime.h>
#include <math.h>

#define NN 10000
#define NE 160000

typedef __attribute__((ext_vector_type(8))) short s8v;
typedef __attribute__((ext_vector_type(4))) float f4v;
typedef unsigned short u16;

// ---- ws byte layout ----
#define OFF_P1HB 0u          // N*32 bf16      = 640000 B
#define OFF_P3HB 640000u     // N*3*32 bf16    = 1920000 B
#define OFF_WB   2560000u    // NWB bf16       = 204800 B
#define OFF_P1N  2764800u    // N*32 f32       = 1280000 B
#define OFF_P3N  4044800u    // N*3*32 f32     = 3840000 B

// ---- wb (ushort element) offsets ----
#define OW1T1 0       // [32 c][72 kpad]  (k<64)
#define OW2T1 2304    // [96 c][40 kpad]  (k<32)
#define OII1T 6144    // [32 c][40 kpad]
#define OW1T3 7424    // [32 c][72 kpad]
#define OW2T3 9728    // [32 c][40 kpad]
#define OII3T 11008   // [32 c][40 kpad]
#define OBLG  12288   // [8 b][96 c][104 kpad]  (k<96)   = 79872
#define OBL3G 92160   // [8 b][32 c][40 kpad]   (k<32)   = 10240
#define NWB   102400

__device__ __forceinline__ short f2b(float f) {
    unsigned u = __float_as_uint(f);
    u += 0x7fffu + ((u >> 16) & 1u);
    return (short)(u >> 16);
}
__device__ __forceinline__ float tanhf_fast(float x) {
    float xc = fminf(9.f, fmaxf(-9.f, x));
    float e = __expf(2.f * xc);
    return (e - 1.f) * __builtin_amdgcn_rcpf(e + 1.f);
}

// ---------------- node prep: p1h/p3h = tanh(x@W+b) -> bf16 ----------------
__global__ __launch_bounds__(256) void node_prep(
    const float* __restrict__ p1, const float* __restrict__ p3,
    const float* __restrict__ pp1_W, const float* __restrict__ pp1_b,
    const float* __restrict__ pp3_W, const float* __restrict__ pp3_b,
    u16* __restrict__ p1hb, u16* __restrict__ p3hb)
{
    __shared__ float Ws[2][32 * 32];
    __shared__ float bsm[2][32];
    int tid = threadIdx.x;
    for (int i = tid; i < 32 * 32; i += 256) { Ws[0][i] = pp1_W[i]; Ws[1][i] = pp3_W[i]; }
    if (tid < 32) { bsm[0][tid] = pp1_b[tid]; bsm[1][tid] = pp3_b[tid]; }
    __syncthreads();
    int idx = blockIdx.x * 256 + tid;
    int n = idx >> 7;
    int r = (idx >> 5) & 3;
    int c = idx & 31;
    int sel = (r == 0) ? 0 : 1;
    const float* in = (r == 0) ? (p1 + n * 32) : (p3 + (n * 3 + (r - 1)) * 32);
    float acc = bsm[sel][c];
    #pragma unroll
    for (int k = 0; k < 32; ++k) acc += in[k] * Ws[sel][k * 32 + c];
    short v = f2b(tanhf(acc));
    if (r == 0) p1hb[n * 32 + c] = (u16)v;
    else        p3hb[(n * 3 + (r - 1)) * 32 + c] = (u16)v;
}

// ---------------- weight prep: transpose/convert to bf16 with pads --------
__global__ __launch_bounds__(256) void wprep(
    const float* __restrict__ W1, const float* __restrict__ W2,
    const float* __restrict__ W3, const float* __restrict__ ii1,
    const float* __restrict__ W13, const float* __restrict__ W23,
    const float* __restrict__ W33, const float* __restrict__ ii3,
    u16* __restrict__ wb)
{
    int i0 = blockIdx.x * 256 + threadIdx.x;
    if (i0 >= NWB) return;
    int i = i0;
    float v = 0.f;
    if (i < 2304) { int c = i / 72, k = i % 72; if (k < 64) v = W1[k * 32 + c]; }
    else if ((i -= 2304) < 3840) { int c = i / 40, k = i % 40; if (k < 32) v = W2[k * 96 + c]; }
    else if ((i -= 3840) < 1280) { int c = i / 40, k = i % 40; if (k < 32) v = ii1[k * 32 + c]; }
    else if ((i -= 1280) < 2304) { int c = i / 72, k = i % 72; if (k < 64) v = W13[k * 32 + c]; }
    else if ((i -= 2304) < 1280) { int c = i / 40, k = i % 40; if (k < 32) v = W23[k * 32 + c]; }
    else if ((i -= 1280) < 1280) { int c = i / 40, k = i % 40; if (k < 32) v = ii3[k * 32 + c]; }
    else if ((i -= 1280) < 79872) {
        int b = i / 9984, r = i % 9984, c = r / 104, k = r % 104;
        if (k < 96) v = W3[k * 768 + c * 8 + b];
    } else {
        i -= 79872;
        int b = i / 1280, r = i % 1280, c = r / 40, k = r % 40;
        if (k < 32) v = W33[k * 256 + c * 8 + b];
    }
    wb[i0] = (u16)f2b(v);
}

// ------- fused edge kernel: 16 edges per 1-wave block (1 M-tile) ----------
// M=1: per-wave regs ~70 (accT 24 + af 12 + accP 8 + temps), well under the
// (64,4) 128-VGPR cap -> no spill (round-6 failure was need>cap; here cap>>need).
// 10000 waves supplied (39/CU) -- continuing the empirically-validated
// "more, shorter waves" axis (M=4->2 gave -21%).
__global__ __launch_bounds__(64, 4) void edge_kernel(
    const u16* __restrict__ p1hb, const u16* __restrict__ p3hb,
    const float* __restrict__ r3, const float* __restrict__ basis,
    const int* __restrict__ idx_i, const int* __restrict__ idx_j,
    const u16* __restrict__ wb,
    const float* __restrict__ b1, const float* __restrict__ b2,
    const float* __restrict__ ii1b,
    const float* __restrict__ b13, const float* __restrict__ b23,
    const float* __restrict__ ii3b,
    float* __restrict__ p1n, float* __restrict__ p3n)
{
    // 5.5 KB LDS, single wave per block
    __shared__ int4 smem4[344];
    char* sw = (char*)smem4;
    int*   sIdxI = (int*)(sw + 0);       // [16]
    int*   sIdxJ = (int*)(sw + 64);      // [16]
    float* sBasT = (float*)(sw + 128);   // [8][16] transposed basis
    float* sR3   = (float*)(sw + 640);   // [3][16]
    u16*   sT1   = (u16*)(sw + 832);     // [16][104] h2 transpose buffer
    u16*   sT2   = (u16*)(sw + 4160);    // [16][40]  small transpose buffer

    const int l   = threadIdx.x & 63;
    const int r16 = l & 15;
    const int kg  = l >> 4;
    const int ebase = blockIdx.x * 16;

    // ---- staging (single wave: in-order LDS, no barriers) ----
    if (l < 16)      sIdxI[l] = idx_i[ebase + l];
    else if (l < 32) sIdxJ[l - 16] = idx_j[ebase + l - 16];
    else if (l < 48) {
        int e = l - 32;
        sR3[e]      = r3[(size_t)(ebase + e) * 3 + 0];
        sR3[16 + e] = r3[(size_t)(ebase + e) * 3 + 1];
        sR3[32 + e] = r3[(size_t)(ebase + e) * 3 + 2];
    }
    if (l < 32) {
        int e = l >> 1, hf = l & 1;
        float4 q = ((const float4*)(basis + (size_t)(ebase + e) * 8))[hf];
        sBasT[(4 * hf + 0) * 16 + e] = q.x;
        sBasT[(4 * hf + 1) * 16 + e] = q.y;
        sBasT[(4 * hf + 2) * 16 + e] = q.z;
        sBasT[(4 * hf + 3) * 16 + e] = q.w;
    }

    // bias registers (per-lane channel slices)
    const float vb1[2]  = { b1[r16],   b1[16 + r16] };
    float vb2[6];
    #pragma unroll
    for (int nt = 0; nt < 6; ++nt) vb2[nt] = b2[16 * nt + r16];
    const float vii1[2] = { ii1b[r16], ii1b[16 + r16] };
    const float vb13[2] = { b13[r16],  b13[16 + r16] };
    const float vb23[2] = { b23[r16],  b23[16 + r16] };
    const float vii3[2] = { ii3b[r16], ii3b[16 + r16] };

    const f4v zf = {0.f, 0.f, 0.f, 0.f};

    // ---- Phase A: pi1 front (h1 -> h2 -> af regs) ----
    s8v af[3];
    f4v accT[6];
    #pragma unroll
    for (int nt = 0; nt < 6; ++nt) accT[nt] = zf;

    {
        const u16* gW1 = wb + OW1T1;
        const u16* gW2 = wb + OW2T1;
        int ni = sIdxI[r16], nj = sIdxJ[r16];
        s8v av0 = *(const s8v*)(p1hb + (size_t)ni * 32 + kg * 8);
        s8v av1 = *(const s8v*)(p1hb + (size_t)nj * 32 + kg * 8);
        #pragma unroll
        for (int nt = 0; nt < 2; ++nt) {
            s8v bv0 = *(const s8v*)(gW1 + (16 * nt + r16) * 72 + 8 * kg);
            s8v bv1 = *(const s8v*)(gW1 + (16 * nt + r16) * 72 + 32 + 8 * kg);
            f4v a = __builtin_amdgcn_mfma_f32_16x16x32_bf16(av0, bv0, zf, 0, 0, 0);
            a = __builtin_amdgcn_mfma_f32_16x16x32_bf16(av1, bv1, a, 0, 0, 0);
            #pragma unroll
            for (int rr = 0; rr < 4; ++rr)
                sT2[(4 * kg + rr) * 40 + 16 * nt + r16] = (u16)f2b(a[rr] + vb1[nt]);
        }
        s8v av2 = *(const s8v*)(sT2 + r16 * 40 + 8 * kg);
        #pragma unroll
        for (int nt = 0; nt < 6; ++nt) {
            s8v bv = *(const s8v*)(gW2 + (16 * nt + r16) * 40 + 8 * kg);
            f4v acc = __builtin_amdgcn_mfma_f32_16x16x32_bf16(av2, bv, zf, 0, 0, 0);
            #pragma unroll
            for (int rr = 0; rr < 4; ++rr)
                sT1[(4 * kg + rr) * 104 + 16 * nt + r16] = (u16)f2b(acc[rr] + vb2[nt]);
        }
        af[0] = *(const s8v*)(sT1 + r16 * 104 + 8 * kg);
        af[1] = *(const s8v*)(sT1 + r16 * 104 + 32 + 8 * kg);
        af[2] = *(const s8v*)(sT1 + r16 * 104 + 64 + 8 * kg);
    }

    // ---- Phase B: pi1-W3 b-form (6 independent nt chains / b) ----
    {
        const u16* gBl = wb + OBLG;
        #pragma unroll 2
        for (int b = 0; b < 8; ++b) {
            float tb[4];
            #pragma unroll
            for (int rr = 0; rr < 4; ++rr)
                tb[rr] = sBasT[b * 16 + 4 * kg + rr];
            #pragma unroll
            for (int nt = 0; nt < 6; ++nt) {
                const u16* bp = gBl + (size_t)b * 9984 + (16 * nt + r16) * 104 + 8 * kg;
                s8v bv0 = *(const s8v*)(bp);
                s8v bv1 = *(const s8v*)(bp + 32);
                s8v bv2 = *(const s8v*)(bp + 64);
                f4v D = __builtin_amdgcn_mfma_f32_16x16x32_bf16(af[0], bv0, zf, 0, 0, 0);
                D = __builtin_amdgcn_mfma_f32_16x16x32_bf16(af[1], bv1, D, 0, 0, 0);
                D = __builtin_amdgcn_mfma_f32_16x16x32_bf16(af[2], bv2, D, 0, 0, 0);
                #pragma unroll
                for (int rr = 0; rr < 4; ++rr)
                    accT[nt][rr] += tb[rr] * D[rr];
            }
        }
    }

    // ---- Phase C: ii1 = tanh(i1_1 @ ii1_W + b) -> atomic p1n[idx_j] ----
    {
        const u16* gII = wb + OII1T;
        #pragma unroll
        for (int nt = 0; nt < 2; ++nt)
            #pragma unroll
            for (int rr = 0; rr < 4; ++rr)
                sT2[(4 * kg + rr) * 40 + 16 * nt + r16] = (u16)f2b(accT[nt][rr]);
        s8v av = *(const s8v*)(sT2 + r16 * 40 + 8 * kg);
        #pragma unroll
        for (int nt = 0; nt < 2; ++nt) {
            s8v bv = *(const s8v*)(gII + (16 * nt + r16) * 40 + 8 * kg);
            f4v ia = __builtin_amdgcn_mfma_f32_16x16x32_bf16(av, bv, zf, 0, 0, 0);
            #pragma unroll
            for (int rr = 0; rr < 4; ++rr) {
                int rowD = 4 * kg + rr;
                atomicAdd(&p1n[(size_t)sIdxJ[rowD] * 32 + 16 * nt + r16],
                          tanhf_fast(ia[rr] + vii1[nt]));
            }
        }
    }

    // ---- Phase D: pi3 branch per Cartesian d ----
    const u16* gW13 = wb + OW1T3;
    const u16* gW23 = wb + OW2T3;
    const u16* gII3 = wb + OII3T;
    const u16* gBl3 = wb + OBL3G;
    for (int d = 0; d < 3; ++d) {
        s8v avG2;
        {
            int ni = sIdxI[r16], nj = sIdxJ[r16];
            s8v av0 = *(const s8v*)(p3hb + ((size_t)ni * 3 + d) * 32 + kg * 8);
            s8v av1 = *(const s8v*)(p3hb + ((size_t)nj * 3 + d) * 32 + kg * 8);
            #pragma unroll
            for (int nt = 0; nt < 2; ++nt) {
                s8v bv0 = *(const s8v*)(gW13 + (16 * nt + r16) * 72 + 8 * kg);
                s8v bv1 = *(const s8v*)(gW13 + (16 * nt + r16) * 72 + 32 + 8 * kg);
                f4v g = __builtin_amdgcn_mfma_f32_16x16x32_bf16(av0, bv0, zf, 0, 0, 0);
                g = __builtin_amdgcn_mfma_f32_16x16x32_bf16(av1, bv1, g, 0, 0, 0);
                #pragma unroll
                for (int rr = 0; rr < 4; ++rr)
                    sT2[(4 * kg + rr) * 40 + 16 * nt + r16] = (u16)f2b(g[rr] + vb13[nt]);
            }
            s8v avg = *(const s8v*)(sT2 + r16 * 40 + 8 * kg);
            #pragma unroll
            for (int nt = 0; nt < 2; ++nt) {
                s8v bv = *(const s8v*)(gW23 + (16 * nt + r16) * 40 + 8 * kg);
                f4v g2 = __builtin_amdgcn_mfma_f32_16x16x32_bf16(avg, bv, zf, 0, 0, 0);
                #pragma unroll
                for (int rr = 0; rr < 4; ++rr)
                    sT2[(4 * kg + rr) * 40 + 16 * nt + r16] = (u16)f2b(g2[rr] + vb23[nt]);
            }
            avG2 = *(const s8v*)(sT2 + r16 * 40 + 8 * kg);
        }
        // W33 b-form
        f4v accP[2];
        accP[0] = zf; accP[1] = zf;
        #pragma unroll 2
        for (int b = 0; b < 8; ++b) {
            float tb[4];
            #pragma unroll
            for (int rr = 0; rr < 4; ++rr)
                tb[rr] = sBasT[b * 16 + 4 * kg + rr];
            #pragma unroll
            for (int nt = 0; nt < 2; ++nt) {
                s8v bv = *(const s8v*)(gBl3 + (size_t)b * 1280 + (16 * nt + r16) * 40 + 8 * kg);
                f4v D = __builtin_amdgcn_mfma_f32_16x16x32_bf16(avG2, bv, zf, 0, 0, 0);
                #pragma unroll
                for (int rr = 0; rr < 4; ++rr)
                    accP[nt][rr] += tb[rr] * D[rr];
            }
        }
        // ii3 + combine + atomic p3n
        #pragma unroll
        for (int nt = 0; nt < 2; ++nt)
            #pragma unroll
            for (int rr = 0; rr < 4; ++rr)
                sT2[(4 * kg + rr) * 40 + 16 * nt + r16] = (u16)f2b(accP[nt][rr]);
        s8v av = *(const s8v*)(sT2 + r16 * 40 + 8 * kg);
        #pragma unroll
        for (int nt = 0; nt < 2; ++nt) {
            s8v bv = *(const s8v*)(gII3 + (16 * nt + r16) * 40 + 8 * kg);
            f4v ja = __builtin_amdgcn_mfma_f32_16x16x32_bf16(av, bv, zf, 0, 0, 0);
            #pragma unroll
            for (int rr = 0; rr < 4; ++rr) {
                int rowD = 4 * kg + rr;
                float i3a = tanhf_fast(ja[rr] + vii3[nt]);
                float val = i3a * accT[2 + nt][rr] + sR3[d * 16 + rowD] * accT[4 + nt][rr];
                atomicAdd(&p3n[((size_t)sIdxJ[rowD] * 3 + d) * 32 + 16 * nt + r16], val);
            }
        }
    }
}

// ---------------- finalize: p1o = sum_d p3n^2 + p1n ; p3o = p3n * p1o -----
__global__ __launch_bounds__(256) void finalize_kernel(
    const float* __restrict__ p1n, const float* __restrict__ p3n,
    float* __restrict__ out)
{
    int t = blockIdx.x * 256 + threadIdx.x;
    int n = t >> 5, c = t & 31;
    float a0 = p3n[(n * 3 + 0) * 32 + c];
    float a1 = p3n[(n * 3 + 1) * 32 + c];
    float a2 = p3n[(n * 3 + 2) * 32 + c];
    float p1o = p1n[t] + a0 * a0 + a1 * a1 + a2 * a2;
    out[t] = p1o;
    float* o3 = out + NN * 32;
    o3[(n * 3 + 0) * 32 + c] = a0 * p1o;
    o3[(n * 3 + 1) * 32 + c] = a1 * p1o;
    o3[(n * 3 + 2) * 32 + c] = a2 * p1o;
}

extern "C" void kernel_launch(void* const* d_in, const int* in_sizes, int n_in,
                              void* d_out, int out_size, void* d_ws, size_t ws_size,
                              hipStream_t stream) {
    const float* p1     = (const float*)d_in[0];
    const float* p3     = (const float*)d_in[1];
    const float* r3     = (const float*)d_in[2];
    const float* basis  = (const float*)d_in[3];
    const int*   idx_i  = (const int*)d_in[4];
    const int*   idx_j  = (const int*)d_in[5];
    const float* pp1_W  = (const float*)d_in[6];
    const float* pp1_b  = (const float*)d_in[7];
    const float* pi1_W1 = (const float*)d_in[8];
    const float* pi1_b1 = (const float*)d_in[9];
    const float* pi1_W2 = (const float*)d_in[10];
    const float* pi1_b2 = (const float*)d_in[11];
    const float* pi1_W3 = (const float*)d_in[12];
    const float* ii1_W  = (const float*)d_in[13];
    const float* ii1_b  = (const float*)d_in[14];
    const float* pp3_W  = (const float*)d_in[15];
    const float* pp3_b  = (const float*)d_in[16];
    const float* pi3_W1 = (const float*)d_in[17];
    const float* pi3_b1 = (const float*)d_in[18];
    const float* pi3_W2 = (const float*)d_in[19];
    const float* pi3_b2 = (const float*)d_in[20];
    const float* pi3_W3 = (const float*)d_in[21];
    const float* ii3_W  = (const float*)d_in[22];
    const float* ii3_b  = (const float*)d_in[23];

    char* ws = (char*)d_ws;
    u16*   p1hb = (u16*)(ws + OFF_P1HB);
    u16*   p3hb = (u16*)(ws + OFF_P3HB);
    u16*   wb   = (u16*)(ws + OFF_WB);
    float* p1n  = (float*)(ws + OFF_P1N);
    float* p3n  = (float*)(ws + OFF_P3N);

    hipMemsetAsync(p1n, 0, 5120000, stream);

    node_prep<<<dim3(5000), dim3(256), 0, stream>>>(p1, p3, pp1_W, pp1_b, pp3_W, pp3_b, p1hb, p3hb);
    wprep<<<dim3((NWB + 255) / 256), dim3(256), 0, stream>>>(
        pi1_W1, pi1_W2, pi1_W3, ii1_W, pi3_W1, pi3_W2, pi3_W3, ii3_W, wb);

    edge_kernel<<<dim3(NE / 16), dim3(64), 0, stream>>>(
        p1hb, p3hb, r3, basis, idx_i, idx_j, wb,
        pi1_b1, pi1_b2, ii1_b, pi3_b1, pi3_b2, ii3_b,
        p1n, p3n);

    finalize_kernel<<<dim3(1250), dim3(256), 0, stream>>>(p1n, p3n, (float*)d_out);
}